// Round 2
// baseline (338.149 us; speedup 1.0000x reference)
//
#include <hip/hip_runtime.h>

// ---------------- problem constants ----------------
#define N_NODES 10000
#define T_STEPS 8
#define F_IN 4
#define H1 16
#define HEADS 4
#define H2 32
#define G 32
#define PW 16
#define E_EDGES 160000
#define CAP 64                     // padded bucket slots per node (max real deg ~34)
#define NREP 128                   // curh atomic replicas

__device__ __forceinline__ float lrelu(float x) { return x > 0.f ? x : 0.2f * x; }
__device__ __forceinline__ float eluf(float x) { return x > 0.f ? x : (expf(x) - 1.f); }
__device__ __forceinline__ float sigmoidf(float x) { return 1.f / (1.f + expf(-x)); }
// sum over the 8 lanes sharing the same t (lane = es*8 + t)
__device__ __forceinline__ float g8sum(float v) {
    v += __shfl_xor(v, 8);
    v += __shfl_xor(v, 16);
    v += __shfl_xor(v, 32);
    return v;
}
// bf16 <-> fp32
__device__ __forceinline__ float bf2f(unsigned int u) {
    return __uint_as_float(u << 16);
}
__device__ __forceinline__ unsigned short f2bf(float f) {
    unsigned b = __float_as_uint(f);
    return (unsigned short)((b + 0x7FFFu + ((b >> 16) & 1u)) >> 16);
}

// ---------------- padded-bucket scatter (edges only; self-loops virtual) ----------------
__global__ void __launch_bounds__(256) k_scatter(
        const int* __restrict__ ei, int* __restrict__ cnt, int* __restrict__ colsrc) {
    int idx = blockIdx.x * 256 + threadIdx.x;
    if (idx >= E_EDGES) return;
    int src = ei[idx];
    int dst = ei[E_EDGES + idx];
    int pos = atomicAdd(&cnt[dst], 1);
    if (pos < CAP) colsrc[(dst << 6) + pos] = src;  // guard: memory-safe even if pathological
}

// ---------------- L1: one wave per node, lane = es*8 + t, direct-exp softmax ----------------
// asrc/adst computed on the fly from gathered dyn rows (VA/VD = W1@a in LDS).
// u_h = sum_e w_e^h * x[src_e]; out = (u_h @ W1)/s_h, ELU; fused W2 -> z2 bf16.
__global__ void __launch_bounds__(256) k_l1_node(
        const int* __restrict__ cnt, const int* __restrict__ colsrc,
        const float4* __restrict__ dyn, const float* __restrict__ W1,
        const float* __restrict__ as1, const float* __restrict__ ad1,
        const float* __restrict__ b1, const float* __restrict__ W2,
        const float* __restrict__ as2, const float* __restrict__ ad2,
        unsigned short* __restrict__ z2g, float* __restrict__ asrc2,
        float* __restrict__ adst2) {
    __shared__ float sVA[16], sVD[16];  // [d*4+h]
    __shared__ float sW1[256], sB1[64], sW2[64 * 32];
    __shared__ float sAs2[32], sAd2[32];
    __shared__ float sRow[4][8 * 65];
    int tid = threadIdx.x;
    for (int i = tid; i < 64 * 32; i += 256) sW2[i] = W2[i];
    sW1[tid] = W1[tid];
    if (tid < 64) sB1[tid] = b1[tid];
    if (tid < 32) { sAs2[tid] = as2[tid]; sAd2[tid] = ad2[tid]; }
    if (tid < 32) {
        int q = tid & 15, d = q >> 2, hh = q & 3;
        const float* a = (tid < 16) ? as1 : ad1;
        float acc = 0.f;
#pragma unroll
        for (int c = 0; c < 16; ++c) acc += W1[d * 64 + hh * 16 + c] * a[hh * 16 + c];
        if (tid < 16) sVA[q] = acc;
        else sVD[q] = acc;
    }
    __syncthreads();

    int lane = tid & 63, wslot = tid >> 6;
    int n = blockIdx.x * 4 + wslot;
    int t = lane & 7, es = lane >> 3;
    int beg = n << 6;
    int dreal = cnt[n]; if (dreal > CAP) dreal = CAP;
    int deg = dreal + 1;  // + virtual self loop
    const float4 xo = dyn[(n << 3) + t];
    float ad0 = xo.x * sVD[0] + xo.y * sVD[4] + xo.z * sVD[8]  + xo.w * sVD[12];
    float ad1v = xo.x * sVD[1] + xo.y * sVD[5] + xo.z * sVD[9]  + xo.w * sVD[13];
    float ad2v = xo.x * sVD[2] + xo.y * sVD[6] + xo.z * sVD[10] + xo.w * sVD[14];
    float ad3v = xo.x * sVD[3] + xo.y * sVD[7] + xo.z * sVD[11] + xo.w * sVD[15];

    float s0 = 0.f, s1 = 0.f, s2 = 0.f, s3 = 0.f;
    float u[16];
#pragma unroll
    for (int i = 0; i < 16; ++i) u[i] = 0.f;

    for (int e0 = 0; e0 < deg; e0 += 8) {
        int e = e0 + es;
        bool act = e < deg;
        int src = (e < deg - 1) ? colsrc[beg + e] : n;  // virtual self-loop at tail
        const float4 x4 = dyn[(src << 3) + t];
        float l0 = x4.x * sVA[0] + x4.y * sVA[4] + x4.z * sVA[8]  + x4.w * sVA[12] + ad0;
        float l1 = x4.x * sVA[1] + x4.y * sVA[5] + x4.z * sVA[9]  + x4.w * sVA[13] + ad1v;
        float l2 = x4.x * sVA[2] + x4.y * sVA[6] + x4.z * sVA[10] + x4.w * sVA[14] + ad2v;
        float l3 = x4.x * sVA[3] + x4.y * sVA[7] + x4.z * sVA[11] + x4.w * sVA[15] + ad3v;
        float w0 = act ? expf(lrelu(l0)) : 0.f;
        float w1 = act ? expf(lrelu(l1)) : 0.f;
        float w2 = act ? expf(lrelu(l2)) : 0.f;
        float w3 = act ? expf(lrelu(l3)) : 0.f;
        s0 += w0; s1 += w1; s2 += w2; s3 += w3;
        u[0]  += w0 * x4.x; u[1]  += w0 * x4.y; u[2]  += w0 * x4.z; u[3]  += w0 * x4.w;
        u[4]  += w1 * x4.x; u[5]  += w1 * x4.y; u[6]  += w1 * x4.z; u[7]  += w1 * x4.w;
        u[8]  += w2 * x4.x; u[9]  += w2 * x4.y; u[10] += w2 * x4.z; u[11] += w2 * x4.w;
        u[12] += w3 * x4.x; u[13] += w3 * x4.y; u[14] += w3 * x4.z; u[15] += w3 * x4.w;
    }
    // reduce s and u over the 8 es-lanes (per t)
    s0 = g8sum(s0); s1 = g8sum(s1); s2 = g8sum(s2); s3 = g8sum(s3);
#pragma unroll
    for (int i = 0; i < 16; ++i) u[i] = g8sum(u[i]);

    // epilogue: lane covers channels c = es*8+j (head h = es>>1 fixed per lane)
    int h = es >> 1;
    float uh0 = (h == 0) ? u[0] : (h == 1) ? u[4] : (h == 2) ? u[8]  : u[12];
    float uh1 = (h == 0) ? u[1] : (h == 1) ? u[5] : (h == 2) ? u[9]  : u[13];
    float uh2 = (h == 0) ? u[2] : (h == 1) ? u[6] : (h == 2) ? u[10] : u[14];
    float uh3 = (h == 0) ? u[3] : (h == 1) ? u[7] : (h == 2) ? u[11] : u[15];
    float sh = (h == 0) ? s0 : (h == 1) ? s1 : (h == 2) ? s2 : s3;
    float inv = 1.f / sh;
#pragma unroll
    for (int j = 0; j < 8; ++j) {
        int c = es * 8 + j;
        float acc = uh0 * sW1[c] + uh1 * sW1[64 + c] + uh2 * sW1[128 + c] + uh3 * sW1[192 + c];
        sRow[wslot][t * 65 + c] = eluf(acc * inv + sB1[c]);
    }
    __syncthreads();
    // fused W2 projection: lane computes k = es*4 .. es*4+3 for its t
    float z0 = 0.f, z1v = 0.f, z2v = 0.f, z3v = 0.f;
#pragma unroll 8
    for (int j = 0; j < 64; ++j) {
        float r = sRow[wslot][t * 65 + j];
        const float4 w4 = *reinterpret_cast<const float4*>(&sW2[j * 32 + es * 4]);
        z0 += r * w4.x; z1v += r * w4.y; z2v += r * w4.z; z3v += r * w4.w;
    }
    int wid8 = (n << 3) + t;
    unsigned int p0 = (unsigned)f2bf(z0) | ((unsigned)f2bf(z1v) << 16);
    unsigned int p1 = (unsigned)f2bf(z2v) | ((unsigned)f2bf(z3v) << 16);
    *reinterpret_cast<uint2*>(z2g + (size_t)wid8 * 32 + es * 4) = make_uint2(p0, p1);
    float pa = z0 * sAs2[es * 4] + z1v * sAs2[es * 4 + 1] + z2v * sAs2[es * 4 + 2] + z3v * sAs2[es * 4 + 3];
    float pd = z0 * sAd2[es * 4] + z1v * sAd2[es * 4 + 1] + z2v * sAd2[es * 4 + 2] + z3v * sAd2[es * 4 + 3];
    pa = g8sum(pa);
    pd = g8sum(pd);
    if (es == 0) { asrc2[wid8] = pa; adst2[wid8] = pd; }
}

// ---------------- L2 + head: one wave per node, single-phase direct-exp; last block runs head --
__global__ void __launch_bounds__(256) k_l2_head(
        const int* __restrict__ cnt, const int* __restrict__ colsrc,
        const float* __restrict__ asrc, const float* __restrict__ adst,
        const unsigned short* __restrict__ z2, const float* __restrict__ b2,
        float* __restrict__ part, int* __restrict__ done,
        const float* __restrict__ h0,
        const float* __restrict__ W_ih, const float* __restrict__ W_hh,
        const float* __restrict__ b_ih, const float* __restrict__ b_hh,
        const float* __restrict__ Wi, const float* __restrict__ bi,
        const float* __restrict__ Wr, const float* __restrict__ br,
        const float* __restrict__ Ws, const float* __restrict__ bs,
        const float* __restrict__ cI, const float* __restrict__ cR,
        const float* __restrict__ Nptr, const float* __restrict__ Ivec,
        const float* __restrict__ Rvec, float* __restrict__ out) {
    __shared__ float sB2[32];
    __shared__ float sPart[256];
    __shared__ int sLast;
    int tid = threadIdx.x;
    if (tid < 32) sB2[tid] = b2[tid];
    sPart[tid] = 0.f;
    __syncthreads();

    int lane = tid & 63, wslot = tid >> 6;
    int n = blockIdx.x * 4 + wslot;
    int t2 = lane >> 3, cg = lane & 7;     // lane owns (t2, 4-ch group cg)
    int beg = n << 6;
    int dreal = cnt[n]; if (dreal > CAP) dreal = CAP;
    int deg = dreal + 1;  // + virtual self loop
    float ad = adst[(n << 3) + t2];
    const unsigned short* zb = z2 + t2 * 32 + cg * 4;  // + src*256

    float s = 0.f;
    float a0 = 0.f, a1 = 0.f, a2 = 0.f, a3 = 0.f;
    for (int e = 0; e < deg; ++e) {
        int src = (e < deg - 1) ? colsrc[beg + e] : n;  // virtual self-loop at tail
        float av = asrc[(src << 3) + t2];
        uint2 pz = *reinterpret_cast<const uint2*>(zb + (size_t)src * 256);
        float w = expf(lrelu(av + ad));
        s += w;
        a0 += w * bf2f(pz.x & 0xFFFFu);
        a1 += w * bf2f(pz.x >> 16);
        a2 += w * bf2f(pz.y & 0xFFFFu);
        a3 += w * bf2f(pz.y >> 16);
    }
    float invs = 1.f / s;
    int cbase = cg * 4;
    float v0 = eluf(a0 * invs + sB2[cbase]);
    float v1 = eluf(a1 * invs + sB2[cbase + 1]);
    float v2 = eluf(a2 * invs + sB2[cbase + 2]);
    float v3 = eluf(a3 * invs + sB2[cbase + 3]);
    int pidx = t2 * 32 + cbase;
    atomicAdd(&sPart[pidx], v0);
    atomicAdd(&sPart[pidx + 1], v1);
    atomicAdd(&sPart[pidx + 2], v2);
    atomicAdd(&sPart[pidx + 3], v3);
    __syncthreads();
    atomicAdd(&part[((blockIdx.x & (NREP - 1)) << 8) + tid], sPart[tid]);

    // ---- last-block-done: run the head inline ----
    __threadfence();
    if (tid == 0) {
        int prev = atomicAdd(done, 1);
        sLast = (prev == (int)gridDim.x - 1) ? 1 : 0;
    }
    __syncthreads();
    if (!sLast) return;
    __threadfence();

    __shared__ float xs[256];  // cur_h [8][32]
    __shared__ float h[32], gi[96], gh[96], hnew[32], hs[T_STEPS * 32], sirv[16];
    const float invN = 1.0f / (float)N_NODES;
    int j = tid;
    if (j < 128) {
#pragma unroll
        for (int p = 0; p < 2; ++p) {
            int e = j + p * 128;
            float sum = 0.f;
            for (int r = 0; r < NREP; ++r) sum += part[r * 256 + e];
            xs[e] = sum * invN;
        }
    }
    if (j < 32) h[j] = h0[j];
    __syncthreads();
    for (int t = 0; t < T_STEPS; ++t) {
        if (j < 96) {
            float accI = b_ih[j], accH = b_hh[j];
            for (int k = 0; k < 32; ++k) {
                accI += W_ih[j * 32 + k] * xs[t * 32 + k];
                accH += W_hh[j * 32 + k] * h[k];
            }
            gi[j] = accI;
            gh[j] = accH;
        }
        __syncthreads();
        if (j < 32) {
            float r = sigmoidf(gi[j] + gh[j]);
            float zg = sigmoidf(gi[32 + j] + gh[32 + j]);
            float ng = tanhf(gi[64 + j] + r * gh[64 + j]);
            hnew[j] = (1.f - zg) * ng + zg * h[j];
        }
        __syncthreads();
        if (j < 32) {
            h[j] = hnew[j];
            hs[t * 32 + j] = hnew[j];
        }
        __syncthreads();
    }
    if (j < 32) out[512 + j] = h[j];  // h_final
    if (j < 128) {
        int t = j >> 4, p = j & 15;
        float accI = bi[p], accR = br[p];
        for (int k = 0; k < 34; ++k) {
            float hck = (k < 32) ? hs[t * 32 + k] : (k == 32 ? cI[t] : cR[t]);
            accI += hck * Wi[p * 34 + k];
            accR += hck * Wr[p * 34 + k];
        }
        out[j] = accI;
        out[128 + j] = accR;
    }
    if (j < 16) {
        int t = j >> 1, q = j & 1;
        float acc = bs[q];
        for (int k = 0; k < 34; ++k) {
            float hck = (k < 32) ? hs[t * 32 + k] : (k == 32 ? cI[t] : cR[t]);
            acc += hck * Ws[q * 34 + k];
        }
        sirv[j] = acc;
    }
    __syncthreads();
    if (j < 8) {
        int t = j;
        float alpha = sigmoidf(sirv[2 * t]);
        float beta = sigmoidf(sirv[2 * t + 1]);
        float Np = Nptr[0];
        float lI = Ivec[t], lR = Rvec[t];
        for (int p = 0; p < PW; ++p) {
            float lS = Np - lI - lR;
            float dI = alpha * lI * (lS / Np) - beta * lI;
            float dR = beta * lI;
            out[256 + t * 16 + p] = dI;
            out[384 + t * 16 + p] = dR;
            lI += dI;
            lR += dR;
        }
    }
}

extern "C" void kernel_launch(void* const* d_in, const int* in_sizes, int n_in,
                              void* d_out, int out_size, void* d_ws, size_t ws_size,
                              hipStream_t stream) {
    const float* dyn = (const float*)d_in[0];
    const float* cI = (const float*)d_in[1];
    const float* cR = (const float*)d_in[2];
    const float* Nptr = (const float*)d_in[3];
    const float* Ivec = (const float*)d_in[4];
    const float* Rvec = (const float*)d_in[5];
    const int* ei = (const int*)d_in[6];
    const float* h0 = (const float*)d_in[7];
    const float* W1 = (const float*)d_in[8];
    const float* as1 = (const float*)d_in[9];
    const float* ad1 = (const float*)d_in[10];
    const float* b1 = (const float*)d_in[11];
    const float* W2 = (const float*)d_in[12];
    const float* as2 = (const float*)d_in[13];
    const float* ad2 = (const float*)d_in[14];
    const float* b2 = (const float*)d_in[15];
    const float* W_ih = (const float*)d_in[16];
    const float* W_hh = (const float*)d_in[17];
    const float* b_ih = (const float*)d_in[18];
    const float* b_hh = (const float*)d_in[19];
    const float* Wi = (const float*)d_in[20];
    const float* bi = (const float*)d_in[21];
    const float* Wr = (const float*)d_in[22];
    const float* br = (const float*)d_in[23];
    const float* Ws = (const float*)d_in[24];
    const float* bs = (const float*)d_in[25];
    float* out = (float*)d_out;

    char* ws = (char*)d_ws;
    size_t off = 0;
    auto alloc = [&](size_t bytes) {
        void* p = ws + off;
        off += (bytes + 255) & ~(size_t)255;
        return p;
    };
    const size_t TN = (size_t)T_STEPS * N_NODES;
    // cnt, done, part adjacent -> single memset
    int* cnt = (int*)alloc(N_NODES * 4);
    int* done = (int*)alloc(4);
    float* part = (float*)alloc((size_t)NREP * 256 * 4);
    size_t zero_bytes = off;
    unsigned short* z2 = (unsigned short*)alloc(TN * 32 * 2);
    float* asrc2 = (float*)alloc(TN * 4);
    float* adst2 = (float*)alloc(TN * 4);
    int* colsrc = (int*)alloc((size_t)N_NODES * CAP * 4);
    (void)ws_size; (void)in_sizes; (void)n_in; (void)out_size;

    const int BT = 256;
    hipMemsetAsync(cnt, 0, zero_bytes, stream);
    int gEdge = (E_EDGES + BT - 1) / BT;            // 625
    k_scatter<<<gEdge, BT, 0, stream>>>(ei, cnt, colsrc);
    k_l1_node<<<N_NODES / 4, BT, 0, stream>>>(cnt, colsrc, (const float4*)dyn,
                                              W1, as1, ad1, b1, W2, as2, ad2,
                                              z2, asrc2, adst2);
    k_l2_head<<<N_NODES / 4, BT, 0, stream>>>(cnt, colsrc, asrc2, adst2, z2, b2, part, done,
                                              h0, W_ih, W_hh, b_ih, b_hh, Wi, bi, Wr, br,
                                              Ws, bs, cI, cR, Nptr, Ivec, Rvec, out);
}

// Round 3
// 189.870 us; speedup vs baseline: 1.7810x; 1.7810x over previous
//
#include <hip/hip_runtime.h>

// ---------------- problem constants ----------------
#define N_NODES 10000
#define T_STEPS 8
#define F_IN 4
#define H1 16
#define HEADS 4
#define H2 32
#define G 32
#define PW 16
#define E_EDGES 160000
#define CAP 64                     // padded bucket slots per node (max real deg ~34)
#define NREP 128                   // curh atomic replicas

__device__ __forceinline__ float lrelu(float x) { return x > 0.f ? x : 0.2f * x; }
__device__ __forceinline__ float eluf(float x) { return x > 0.f ? x : (expf(x) - 1.f); }
__device__ __forceinline__ float sigmoidf(float x) { return 1.f / (1.f + expf(-x)); }
// sum over the 8 lanes sharing the same t (lane = es*8 + t)
__device__ __forceinline__ float g8sum(float v) {
    v += __shfl_xor(v, 8);
    v += __shfl_xor(v, 16);
    v += __shfl_xor(v, 32);
    return v;
}
// bf16 <-> fp32
__device__ __forceinline__ float bf2f(unsigned int u) {
    return __uint_as_float(u << 16);
}
__device__ __forceinline__ unsigned short f2bf(float f) {
    unsigned b = __float_as_uint(f);
    return (unsigned short)((b + 0x7FFFu + ((b >> 16) & 1u)) >> 16);
}

// ---------------- padded-bucket scatter (edges only; self-loops virtual) ----------------
__global__ void __launch_bounds__(256) k_scatter(
        const int* __restrict__ ei, int* __restrict__ cnt, int* __restrict__ colsrc) {
    int idx = blockIdx.x * 256 + threadIdx.x;
    if (idx >= E_EDGES) return;
    int src = ei[idx];
    int dst = ei[E_EDGES + idx];
    int pos = atomicAdd(&cnt[dst], 1);
    if (pos < CAP) colsrc[(dst << 6) + pos] = src;  // guard: memory-safe even if pathological
}

// ---------------- L1: one wave per node, lane = es*8 + t, direct-exp softmax ----------------
// asrc/adst computed on the fly from gathered dyn rows (VA/VD = W1@a in LDS).
// u_h = sum_e w_e^h * x[src_e]; out = (u_h @ W1)/s_h, ELU; fused W2 -> z2 bf16.
__global__ void __launch_bounds__(256) k_l1_node(
        const int* __restrict__ cnt, const int* __restrict__ colsrc,
        const float4* __restrict__ dyn, const float* __restrict__ W1,
        const float* __restrict__ as1, const float* __restrict__ ad1,
        const float* __restrict__ b1, const float* __restrict__ W2,
        const float* __restrict__ as2, const float* __restrict__ ad2,
        unsigned short* __restrict__ z2g, float* __restrict__ asrc2,
        float* __restrict__ adst2) {
    __shared__ float sVA[16], sVD[16];  // [d*4+h]
    __shared__ float sW1[256], sB1[64], sW2[64 * 32];
    __shared__ float sAs2[32], sAd2[32];
    __shared__ float sRow[4][8 * 65];
    int tid = threadIdx.x;
    for (int i = tid; i < 64 * 32; i += 256) sW2[i] = W2[i];
    sW1[tid] = W1[tid];
    if (tid < 64) sB1[tid] = b1[tid];
    if (tid < 32) { sAs2[tid] = as2[tid]; sAd2[tid] = ad2[tid]; }
    if (tid < 32) {
        int q = tid & 15, d = q >> 2, hh = q & 3;
        const float* a = (tid < 16) ? as1 : ad1;
        float acc = 0.f;
#pragma unroll
        for (int c = 0; c < 16; ++c) acc += W1[d * 64 + hh * 16 + c] * a[hh * 16 + c];
        if (tid < 16) sVA[q] = acc;
        else sVD[q] = acc;
    }
    __syncthreads();

    int lane = tid & 63, wslot = tid >> 6;
    int n = blockIdx.x * 4 + wslot;
    int t = lane & 7, es = lane >> 3;
    int beg = n << 6;
    int dreal = cnt[n]; if (dreal > CAP) dreal = CAP;
    int deg = dreal + 1;  // + virtual self loop
    const float4 xo = dyn[(n << 3) + t];
    float ad0 = xo.x * sVD[0] + xo.y * sVD[4] + xo.z * sVD[8]  + xo.w * sVD[12];
    float ad1v = xo.x * sVD[1] + xo.y * sVD[5] + xo.z * sVD[9]  + xo.w * sVD[13];
    float ad2v = xo.x * sVD[2] + xo.y * sVD[6] + xo.z * sVD[10] + xo.w * sVD[14];
    float ad3v = xo.x * sVD[3] + xo.y * sVD[7] + xo.z * sVD[11] + xo.w * sVD[15];

    float s0 = 0.f, s1 = 0.f, s2 = 0.f, s3 = 0.f;
    float u[16];
#pragma unroll
    for (int i = 0; i < 16; ++i) u[i] = 0.f;

    for (int e0 = 0; e0 < deg; e0 += 8) {
        int e = e0 + es;
        bool act = e < deg;
        int src = (e < deg - 1) ? colsrc[beg + e] : n;  // virtual self-loop at tail
        const float4 x4 = dyn[(src << 3) + t];
        float l0 = x4.x * sVA[0] + x4.y * sVA[4] + x4.z * sVA[8]  + x4.w * sVA[12] + ad0;
        float l1 = x4.x * sVA[1] + x4.y * sVA[5] + x4.z * sVA[9]  + x4.w * sVA[13] + ad1v;
        float l2 = x4.x * sVA[2] + x4.y * sVA[6] + x4.z * sVA[10] + x4.w * sVA[14] + ad2v;
        float l3 = x4.x * sVA[3] + x4.y * sVA[7] + x4.z * sVA[11] + x4.w * sVA[15] + ad3v;
        float w0 = act ? expf(lrelu(l0)) : 0.f;
        float w1 = act ? expf(lrelu(l1)) : 0.f;
        float w2 = act ? expf(lrelu(l2)) : 0.f;
        float w3 = act ? expf(lrelu(l3)) : 0.f;
        s0 += w0; s1 += w1; s2 += w2; s3 += w3;
        u[0]  += w0 * x4.x; u[1]  += w0 * x4.y; u[2]  += w0 * x4.z; u[3]  += w0 * x4.w;
        u[4]  += w1 * x4.x; u[5]  += w1 * x4.y; u[6]  += w1 * x4.z; u[7]  += w1 * x4.w;
        u[8]  += w2 * x4.x; u[9]  += w2 * x4.y; u[10] += w2 * x4.z; u[11] += w2 * x4.w;
        u[12] += w3 * x4.x; u[13] += w3 * x4.y; u[14] += w3 * x4.z; u[15] += w3 * x4.w;
    }
    // reduce s and u over the 8 es-lanes (per t)
    s0 = g8sum(s0); s1 = g8sum(s1); s2 = g8sum(s2); s3 = g8sum(s3);
#pragma unroll
    for (int i = 0; i < 16; ++i) u[i] = g8sum(u[i]);

    // epilogue: lane covers channels c = es*8+j (head h = es>>1 fixed per lane)
    int h = es >> 1;
    float uh0 = (h == 0) ? u[0] : (h == 1) ? u[4] : (h == 2) ? u[8]  : u[12];
    float uh1 = (h == 0) ? u[1] : (h == 1) ? u[5] : (h == 2) ? u[9]  : u[13];
    float uh2 = (h == 0) ? u[2] : (h == 1) ? u[6] : (h == 2) ? u[10] : u[14];
    float uh3 = (h == 0) ? u[3] : (h == 1) ? u[7] : (h == 2) ? u[11] : u[15];
    float sh = (h == 0) ? s0 : (h == 1) ? s1 : (h == 2) ? s2 : s3;
    float inv = 1.f / sh;
#pragma unroll
    for (int j = 0; j < 8; ++j) {
        int c = es * 8 + j;
        float acc = uh0 * sW1[c] + uh1 * sW1[64 + c] + uh2 * sW1[128 + c] + uh3 * sW1[192 + c];
        sRow[wslot][t * 65 + c] = eluf(acc * inv + sB1[c]);
    }
    __syncthreads();
    // fused W2 projection: lane computes k = es*4 .. es*4+3 for its t
    float z0 = 0.f, z1v = 0.f, z2v = 0.f, z3v = 0.f;
#pragma unroll 8
    for (int j = 0; j < 64; ++j) {
        float r = sRow[wslot][t * 65 + j];
        const float4 w4 = *reinterpret_cast<const float4*>(&sW2[j * 32 + es * 4]);
        z0 += r * w4.x; z1v += r * w4.y; z2v += r * w4.z; z3v += r * w4.w;
    }
    int wid8 = (n << 3) + t;
    unsigned int p0 = (unsigned)f2bf(z0) | ((unsigned)f2bf(z1v) << 16);
    unsigned int p1 = (unsigned)f2bf(z2v) | ((unsigned)f2bf(z3v) << 16);
    *reinterpret_cast<uint2*>(z2g + (size_t)wid8 * 32 + es * 4) = make_uint2(p0, p1);
    float pa = z0 * sAs2[es * 4] + z1v * sAs2[es * 4 + 1] + z2v * sAs2[es * 4 + 2] + z3v * sAs2[es * 4 + 3];
    float pd = z0 * sAd2[es * 4] + z1v * sAd2[es * 4 + 1] + z2v * sAd2[es * 4 + 2] + z3v * sAd2[es * 4 + 3];
    pa = g8sum(pa);
    pd = g8sum(pd);
    if (es == 0) { asrc2[wid8] = pa; adst2[wid8] = pd; }
}

// ---------------- L2: one wave per node; phase A logits->LDS (8-way edge parallel),
// ---------------- phase B coalesced z2 rows; direct exp (no online max) ----------------
__global__ void __launch_bounds__(256) k_l2_node(
        const int* __restrict__ cnt, const int* __restrict__ colsrc,
        const float* __restrict__ asrc, const float* __restrict__ adst,
        const unsigned short* __restrict__ z2, const float* __restrict__ b2,
        float* __restrict__ part) {
    __shared__ int sSrc[4][64];
    __shared__ float sW[4][64 * 8];  // [e][t]
    __shared__ float sS[4][8];
    __shared__ float sB2[32];
    __shared__ float sPart[256];
    int tid = threadIdx.x;
    if (tid < 32) sB2[tid] = b2[tid];
    sPart[tid] = 0.f;
    __syncthreads();

    int lane = tid & 63, wslot = tid >> 6;
    int n = blockIdx.x * 4 + wslot;
    int t = lane & 7, es = lane >> 3;      // phase A mapping
    int t2 = lane >> 3, cg = lane & 7;     // phase B mapping (t2, 4-ch group)
    int beg = n << 6;
    int dreal = cnt[n]; if (dreal > CAP) dreal = CAP;
    int deg = dreal + 1;  // + virtual self loop
    float ad = adst[(n << 3) + t];
    const unsigned short* zb = z2 + t2 * 32 + cg * 4;  // + src*256

    float s = 0.f;
    float a0 = 0.f, a1 = 0.f, a2 = 0.f, a3 = 0.f;
    for (int cb = 0; cb < deg; cb += 64) {
        int cn = deg - cb;
        if (cn > 64) cn = 64;
        int R = (cn + 7) >> 3;
        float ws = 0.f;
#pragma unroll
        for (int r = 0; r < 8; ++r) {
            if (r < R) {
                int e = cb + r * 8 + es;
                bool act = e < deg;
                int src = (e < deg - 1) ? colsrc[beg + e] : n;  // virtual self-loop at tail
                float w = act ? expf(lrelu(asrc[(src << 3) + t] + ad)) : 0.f;
                ws += w;
                sW[wslot][(r * 8 + es) * 8 + t] = w;
                if (t == 0) sSrc[wslot][r * 8 + es] = src;
            }
        }
        s += g8sum(ws);
        // phase B: accumulate this chunk, lane = (t2, cg)
        for (int e = 0; e < cn; ++e) {
            int src = sSrc[wslot][e];
            float w = sW[wslot][e * 8 + t2];
            uint2 pz = *reinterpret_cast<const uint2*>(zb + (size_t)src * 256);
            a0 += w * bf2f(pz.x & 0xFFFFu);
            a1 += w * bf2f(pz.x >> 16);
            a2 += w * bf2f(pz.y & 0xFFFFu);
            a3 += w * bf2f(pz.y >> 16);
        }
    }
    if (es == 0) sS[wslot][t] = s;
    float invs = 1.f / sS[wslot][t2];
    int cbase = cg * 4;
    float v0 = eluf(a0 * invs + sB2[cbase]);
    float v1 = eluf(a1 * invs + sB2[cbase + 1]);
    float v2 = eluf(a2 * invs + sB2[cbase + 2]);
    float v3 = eluf(a3 * invs + sB2[cbase + 3]);
    int pidx = t2 * 32 + cbase;
    atomicAdd(&sPart[pidx], v0);
    atomicAdd(&sPart[pidx + 1], v1);
    atomicAdd(&sPart[pidx + 2], v2);
    atomicAdd(&sPart[pidx + 3], v3);
    __syncthreads();
    atomicAdd(&part[((blockIdx.x & (NREP - 1)) << 8) + tid], sPart[tid]);
}

// ---------------- replica-reduce + GRU + heads + SIR (single block, 128 thr) ----------------
__global__ void k_head(const float* __restrict__ part, const float* __restrict__ h0,
                       const float* __restrict__ W_ih, const float* __restrict__ W_hh,
                       const float* __restrict__ b_ih, const float* __restrict__ b_hh,
                       const float* __restrict__ Wi, const float* __restrict__ bi,
                       const float* __restrict__ Wr, const float* __restrict__ br,
                       const float* __restrict__ Ws, const float* __restrict__ bs,
                       const float* __restrict__ cI, const float* __restrict__ cR,
                       const float* __restrict__ Nptr, const float* __restrict__ Ivec,
                       const float* __restrict__ Rvec, float* __restrict__ out) {
    __shared__ float xs[256];  // cur_h [8][32]
    __shared__ float h[32], gi[96], gh[96], hnew[32], hs[T_STEPS * 32], sirv[16];
    const float invN = 1.0f / (float)N_NODES;
    int j = threadIdx.x;
#pragma unroll
    for (int p = 0; p < 2; ++p) {
        int e = j + p * 128;
        float sum = 0.f;
        for (int r = 0; r < NREP; ++r) sum += part[r * 256 + e];
        xs[e] = sum * invN;
    }
    if (j < 32) h[j] = h0[j];
    __syncthreads();
    for (int t = 0; t < T_STEPS; ++t) {
        if (j < 96) {
            float accI = b_ih[j], accH = b_hh[j];
            for (int k = 0; k < 32; ++k) {
                accI += W_ih[j * 32 + k] * xs[t * 32 + k];
                accH += W_hh[j * 32 + k] * h[k];
            }
            gi[j] = accI;
            gh[j] = accH;
        }
        __syncthreads();
        if (j < 32) {
            float r = sigmoidf(gi[j] + gh[j]);
            float zg = sigmoidf(gi[32 + j] + gh[32 + j]);
            float ng = tanhf(gi[64 + j] + r * gh[64 + j]);
            hnew[j] = (1.f - zg) * ng + zg * h[j];
        }
        __syncthreads();
        if (j < 32) {
            h[j] = hnew[j];
            hs[t * 32 + j] = hnew[j];
        }
        __syncthreads();
    }
    if (j < 32) out[512 + j] = h[j];  // h_final
    {
        int t = j >> 4, p = j & 15;
        float accI = bi[p], accR = br[p];
        for (int k = 0; k < 34; ++k) {
            float hck = (k < 32) ? hs[t * 32 + k] : (k == 32 ? cI[t] : cR[t]);
            accI += hck * Wi[p * 34 + k];
            accR += hck * Wr[p * 34 + k];
        }
        out[j] = accI;
        out[128 + j] = accR;
    }
    if (j < 16) {
        int t = j >> 1, q = j & 1;
        float acc = bs[q];
        for (int k = 0; k < 34; ++k) {
            float hck = (k < 32) ? hs[t * 32 + k] : (k == 32 ? cI[t] : cR[t]);
            acc += hck * Ws[q * 34 + k];
        }
        sirv[j] = acc;
    }
    __syncthreads();
    if (j < 8) {
        int t = j;
        float alpha = sigmoidf(sirv[2 * t]);
        float beta = sigmoidf(sirv[2 * t + 1]);
        float Np = Nptr[0];
        float lI = Ivec[t], lR = Rvec[t];
        for (int p = 0; p < PW; ++p) {
            float lS = Np - lI - lR;
            float dI = alpha * lI * (lS / Np) - beta * lI;
            float dR = beta * lI;
            out[256 + t * 16 + p] = dI;
            out[384 + t * 16 + p] = dR;
            lI += dI;
            lR += dR;
        }
    }
}

extern "C" void kernel_launch(void* const* d_in, const int* in_sizes, int n_in,
                              void* d_out, int out_size, void* d_ws, size_t ws_size,
                              hipStream_t stream) {
    const float* dyn = (const float*)d_in[0];
    const float* cI = (const float*)d_in[1];
    const float* cR = (const float*)d_in[2];
    const float* Nptr = (const float*)d_in[3];
    const float* Ivec = (const float*)d_in[4];
    const float* Rvec = (const float*)d_in[5];
    const int* ei = (const int*)d_in[6];
    const float* h0 = (const float*)d_in[7];
    const float* W1 = (const float*)d_in[8];
    const float* as1 = (const float*)d_in[9];
    const float* ad1 = (const float*)d_in[10];
    const float* b1 = (const float*)d_in[11];
    const float* W2 = (const float*)d_in[12];
    const float* as2 = (const float*)d_in[13];
    const float* ad2 = (const float*)d_in[14];
    const float* b2 = (const float*)d_in[15];
    const float* W_ih = (const float*)d_in[16];
    const float* W_hh = (const float*)d_in[17];
    const float* b_ih = (const float*)d_in[18];
    const float* b_hh = (const float*)d_in[19];
    const float* Wi = (const float*)d_in[20];
    const float* bi = (const float*)d_in[21];
    const float* Wr = (const float*)d_in[22];
    const float* br = (const float*)d_in[23];
    const float* Ws = (const float*)d_in[24];
    const float* bs = (const float*)d_in[25];
    float* out = (float*)d_out;

    char* ws = (char*)d_ws;
    size_t off = 0;
    auto alloc = [&](size_t bytes) {
        void* p = ws + off;
        off += (bytes + 255) & ~(size_t)255;
        return p;
    };
    const size_t TN = (size_t)T_STEPS * N_NODES;
    // cnt and part adjacent -> single memset
    int* cnt = (int*)alloc(N_NODES * 4);
    float* part = (float*)alloc((size_t)NREP * 256 * 4);
    size_t zero_bytes = off;
    unsigned short* z2 = (unsigned short*)alloc(TN * 32 * 2);
    float* asrc2 = (float*)alloc(TN * 4);
    float* adst2 = (float*)alloc(TN * 4);
    int* colsrc = (int*)alloc((size_t)N_NODES * CAP * 4);
    (void)ws_size; (void)in_sizes; (void)n_in; (void)out_size;

    const int BT = 256;
    hipMemsetAsync(cnt, 0, zero_bytes, stream);
    int gEdge = (E_EDGES + BT - 1) / BT;            // 625
    k_scatter<<<gEdge, BT, 0, stream>>>(ei, cnt, colsrc);
    k_l1_node<<<N_NODES / 4, BT, 0, stream>>>(cnt, colsrc, (const float4*)dyn,
                                              W1, as1, ad1, b1, W2, as2, ad2,
                                              z2, asrc2, adst2);
    k_l2_node<<<N_NODES / 4, BT, 0, stream>>>(cnt, colsrc, asrc2, adst2, z2, b2, part);
    k_head<<<1, 128, 0, stream>>>(part, h0, W_ih, W_hh, b_ih, b_hh, Wi, bi, Wr, br, Ws, bs,
                                  cI, cR, Nptr, Ivec, Rvec, out);
}